// Round 1
// baseline (253.416 us; speedup 1.0000x reference)
//
#include <hip/hip_runtime.h>
#include <hip/hip_bf16.h>
#include <math.h>

// Problem dims
constexpr int NB    = 4096;   // batch
constexpr int NBLKc = 12;
constexpr int NDIMc = 24;
constexpr int NMCc  = 256;
constexpr int ROWS2 = NB * NBLKc;     // 49152 rows for the 2->100->100->2 MLPs

// workspace layout (float offsets)
constexpr size_t WS_Y1    = 0;              // NB*24
constexpr size_t WS_YHAT  = 98304;          // NB*24
constexpr size_t WS_YHAT1 = 196608;         // NB*24
constexpr size_t WS_YM    = 294912;         // 24
constexpr size_t WS_U2T   = 294936;         // 24*256 (transposed: [c][m])
constexpr size_t WS_EB    = 301080;         // 24*58 precomputed prior params
// total: 302472 floats = 1.21 MB

__device__ __forceinline__ float lrelu(float x) { return x >= 0.f ? x : 0.01f * x; }

__device__ __forceinline__ float rcp_fast(float x) { return __builtin_amdgcn_rcpf(x); }

// fast tanh via exp, safe for all x (clamped so exp stays finite)
__device__ __forceinline__ float tanh_fast(float x) {
    float xx = fminf(fmaxf(x, -15.f), 15.f);
    float e = __expf(xx + xx);
    return fmaf(-2.f, rcp_fast(e + 1.f), 1.f);
}

// stable softplus (fast-math version for the 100-wide MLPs)
__device__ __forceinline__ float splus(float x) {
    return fmaxf(x, 0.f) + __logf(1.f + __expf(-fabsf(x)));
}
// precise softplus for the (tiny) parameter precompute
__device__ __forceinline__ float splus_precise(float x) {
    return fmaxf(x, 0.f) + log1pf(expf(-fabsf(x)));
}

// exact A2 hex lattice nearest-point quantizer; matches jnp.round (rint = RNE)
__device__ __forceinline__ void hexq(float p0, float p1, float& q0, float& q1) {
    const float S3 = 1.7320508075688772f;
    const float H3 = 0.8660254037844386f;
    float c00 = rintf(p0);
    float c01 = rintf(p1 / S3) * S3;
    float c10 = rintf(p0 - 0.5f) + 0.5f;
    float c11 = rintf((p1 - H3) / S3) * S3 + H3;
    float d0 = (p0 - c00) * (p0 - c00) + (p1 - c01) * (p1 - c01);
    float d1 = (p0 - c10) * (p0 - c10) + (p1 - c11) * (p1 - c11);
    bool take0 = d0 <= d1;
    q0 = take0 ? c00 : c10;
    q1 = take0 ? c01 : c11;
}

// ---------------------------------------------------------------------------
// K0: precompute prior params (softplus(H), tanh(a)) and u2^T = (uG - hexq(uG))^T
// layout per channel c (58 floats): w0[3] b0[3] a0[3] | w1[9] b1[3] a1[3] |
//   w2[9] b2[3] a2[3] | w3[9] b3[3] a3[3] | w4[3] b4[1]
// ---------------------------------------------------------------------------
__global__ __launch_bounds__(256) void k_prep(
    const float* __restrict__ H0p, const float* __restrict__ H1p,
    const float* __restrict__ H2p, const float* __restrict__ H3p,
    const float* __restrict__ H4p,
    const float* __restrict__ b0p, const float* __restrict__ b1p,
    const float* __restrict__ b2p, const float* __restrict__ b3p,
    const float* __restrict__ b4p,
    const float* __restrict__ a0p, const float* __restrict__ a1p,
    const float* __restrict__ a2p, const float* __restrict__ a3p,
    const float* __restrict__ u, float* __restrict__ eb, float* __restrict__ u2t)
{
    int tid = threadIdx.x;
    if (tid < 24) {
        int c = tid;
        float* P = eb + c * 58;
        for (int j = 0; j < 3; ++j) P[j]      = splus_precise(H0p[c*3+j]);
        for (int j = 0; j < 3; ++j) P[3+j]    = b0p[c*3+j];
        for (int j = 0; j < 3; ++j) P[6+j]    = tanhf(a0p[c*3+j]);
        for (int j = 0; j < 9; ++j) P[9+j]    = splus_precise(H1p[c*9+j]);
        for (int j = 0; j < 3; ++j) P[18+j]   = b1p[c*3+j];
        for (int j = 0; j < 3; ++j) P[21+j]   = tanhf(a1p[c*3+j]);
        for (int j = 0; j < 9; ++j) P[24+j]   = splus_precise(H2p[c*9+j]);
        for (int j = 0; j < 3; ++j) P[33+j]   = b2p[c*3+j];
        for (int j = 0; j < 3; ++j) P[36+j]   = tanhf(a2p[c*3+j]);
        for (int j = 0; j < 9; ++j) P[39+j]   = splus_precise(H3p[c*9+j]);
        for (int j = 0; j < 3; ++j) P[48+j]   = b3p[c*3+j];
        for (int j = 0; j < 3; ++j) P[51+j]   = tanhf(a3p[c*3+j]);
        for (int j = 0; j < 3; ++j) P[54+j]   = splus_precise(H4p[c*3+j]);
        P[57] = b4p[c];
    }
    int m = tid;
    if (m < 256) {
        for (int j = 0; j < 12; ++j) {
            float a  = u[m*24 + 2*j];
            float bb = u[m*24 + 2*j + 1];
            // (a,bb) @ G2, G2 = [[1,0],[0.5,sqrt3/2]] (row-vector convention)
            float p0 = fmaf(0.5f, bb, a);
            float p1 = 0.8660254037844386f * bb;
            float q0, q1; hexq(p0, p1, q0, q1);
            u2t[(2*j)   * 256 + m] = p0 - q0;
            u2t[(2*j+1) * 256 + m] = p1 - q1;
        }
    }
}

// ---------------------------------------------------------------------------
// K1/K4: per-row MLP 2 -> 100 (lrelu) -> 100 (lrelu) -> 2 over 49152 rows.
// 64 rows/block, 4 lanes per row split the second-layer i range; h0 kept in
// 100 regs per lane (redundant across the 4 lanes -- only 200 FMAs).
// ---------------------------------------------------------------------------
__global__ __launch_bounds__(256) void k_mlp2(
    const float* __restrict__ in,
    const float* __restrict__ w0, const float* __restrict__ b0,
    const float* __restrict__ w1, const float* __restrict__ b1,
    const float* __restrict__ w2, const float* __restrict__ b2,
    float* __restrict__ out)
{
    __shared__ alignas(16) float sw1[10000];
    __shared__ alignas(16) float sw0[200];
    __shared__ float sb0[100], sb1[100], sw2[200], sb2[2];
    int tid = threadIdx.x;
    for (int i = tid; i < 10000; i += 256) sw1[i] = w1[i];
    for (int i = tid; i < 200; i += 256) { sw0[i] = w0[i]; sw2[i] = w2[i]; }
    for (int i = tid; i < 100; i += 256) { sb0[i] = b0[i]; sb1[i] = b1[i]; }
    if (tid < 2) sb2[tid] = b2[tid];
    __syncthreads();

    int r = tid >> 2, q = tid & 3;
    int row = blockIdx.x * 64 + r;
    float x0 = in[2*row], x1 = in[2*row + 1];

    float h[100];
#pragma unroll
    for (int j = 0; j < 100; ++j)
        h[j] = lrelu(fmaf(sw0[2*j], x0, fmaf(sw0[2*j+1], x1, sb0[j])));

    float y0 = 0.f, y1 = 0.f;
    int i0 = q * 25;
    for (int i = i0; i < i0 + 25; ++i) {
        const float4* wr = (const float4*)&sw1[i * 100];
        float s = sb1[i];
#pragma unroll
        for (int jj = 0; jj < 25; ++jj) {
            float4 w = wr[jj];
            s = fmaf(w.x, h[4*jj], s);
            s = fmaf(w.y, h[4*jj+1], s);
            s = fmaf(w.z, h[4*jj+2], s);
            s = fmaf(w.w, h[4*jj+3], s);
        }
        float a = lrelu(s);
        y0 = fmaf(sw2[i], a, y0);
        y1 = fmaf(sw2[100 + i], a, y1);
    }
    y0 += __shfl_xor(y0, 1); y0 += __shfl_xor(y0, 2);
    y1 += __shfl_xor(y1, 1); y1 += __shfl_xor(y1, 2);
    if (q == 0) {
        out[2*row]     = y0 + sb2[0];
        out[2*row + 1] = y1 + sb2[1];
    }
}

// ---------------------------------------------------------------------------
// K2: deterministic mean over batch + EMA: ym = 0.05*y_mean + 0.95*mean(y1,0)
// ---------------------------------------------------------------------------
__global__ __launch_bounds__(256) void k_mean(
    const float* __restrict__ y1, const float* __restrict__ y_mean,
    float* __restrict__ ym)
{
    __shared__ float red[96];  // 4 waves x 24
    int tid = threadIdx.x;
    float acc[24];
#pragma unroll
    for (int c = 0; c < 24; ++c) acc[c] = 0.f;
    for (int b = tid; b < NB; b += 256) {
        const float4* rp = (const float4*)&y1[b * 24];
#pragma unroll
        for (int k = 0; k < 6; ++k) {
            float4 v = rp[k];
            acc[4*k]   += v.x; acc[4*k+1] += v.y;
            acc[4*k+2] += v.z; acc[4*k+3] += v.w;
        }
    }
#pragma unroll
    for (int c = 0; c < 24; ++c) {
        float v = acc[c];
        for (int off = 1; off < 64; off <<= 1) v += __shfl_xor(v, off);
        if ((tid & 63) == 0) red[(tid >> 6) * 24 + c] = v;
    }
    __syncthreads();
    if (tid < 24) {
        float sv = red[tid] + red[24 + tid] + red[48 + tid] + red[72 + tid];
        ym[tid] = fmaf(0.05f, y_mean[tid], 0.95f * (sv * (1.0f / NB)));
    }
}

// ---------------------------------------------------------------------------
// K3: softplus MLP 24 -> 100 -> 100 -> 24 (no biases), tiled 16 rows/block.
// MODE 0: input = y1 - ym, output = hexq(mlp(...))  -> yhat
// MODE 1: input = yhat,    output = mlp(...) + ym   -> yhat1
// ---------------------------------------------------------------------------
template <int MODE>
__global__ __launch_bounds__(256) void k_mlp24(
    const float* __restrict__ in,
    const float* __restrict__ w0, const float* __restrict__ w1,
    const float* __restrict__ w2,
    const float* __restrict__ ymg, float* __restrict__ out)
{
    __shared__ alignas(16) float sw0[2400];
    __shared__ alignas(16) float sw1[10000];
    __shared__ alignas(16) float sw2[2400];
    __shared__ alignas(16) float X[16 * 24];
    __shared__ alignas(16) float Ha[16 * 100];
    __shared__ alignas(16) float Hb[16 * 100];
    __shared__ float O[16 * 24];
    __shared__ float sym[24];

    int tid = threadIdx.x;
    int row0 = blockIdx.x * 16;
    for (int i = tid; i < 2400; i += 256) { sw0[i] = w0[i]; sw2[i] = w2[i]; }
    for (int i = tid; i < 10000; i += 256) sw1[i] = w1[i];
    if (tid < 24) sym[tid] = ymg[tid];
    for (int e = tid; e < 16 * 24; e += 256) {
        float v = in[row0 * 24 + e];
        if (MODE == 0) v -= ymg[e % 24];
        X[e] = v;
    }
    __syncthreads();

    int r = tid >> 4, s = tid & 15;
    // layer 1: H0 = softplus(X @ w0^T)
    for (int k = 0; k < 7; ++k) {
        int i = s + 16 * k;
        if (i < 100) {
            const float4* wr = (const float4*)&sw0[i * 24];
            const float4* xr = (const float4*)&X[r * 24];
            float acc = 0.f;
#pragma unroll
            for (int jj = 0; jj < 6; ++jj) {
                float4 w = wr[jj], xv = xr[jj];
                acc = fmaf(w.x, xv.x, acc); acc = fmaf(w.y, xv.y, acc);
                acc = fmaf(w.z, xv.z, acc); acc = fmaf(w.w, xv.w, acc);
            }
            Ha[r * 100 + i] = splus(acc);
        }
    }
    __syncthreads();
    // layer 2: H1 = softplus(H0 @ w1^T)
    for (int k = 0; k < 7; ++k) {
        int i = s + 16 * k;
        if (i < 100) {
            const float4* wr = (const float4*)&sw1[i * 100];
            const float4* hr = (const float4*)&Ha[r * 100];
            float acc = 0.f;
#pragma unroll
            for (int jj = 0; jj < 25; ++jj) {
                float4 w = wr[jj], hv = hr[jj];
                acc = fmaf(w.x, hv.x, acc); acc = fmaf(w.y, hv.y, acc);
                acc = fmaf(w.z, hv.z, acc); acc = fmaf(w.w, hv.w, acc);
            }
            Hb[r * 100 + i] = splus(acc);
        }
    }
    __syncthreads();
    // layer 3: O = H1 @ w2^T (no activation)
    for (int e = tid; e < 16 * 24; e += 256) {
        int rr = e / 24, c = e - rr * 24;
        const float4* wr = (const float4*)&sw2[c * 100];
        const float4* hr = (const float4*)&Hb[rr * 100];
        float acc = 0.f;
#pragma unroll
        for (int jj = 0; jj < 25; ++jj) {
            float4 w = wr[jj], hv = hr[jj];
            acc = fmaf(w.x, hv.x, acc); acc = fmaf(w.y, hv.y, acc);
            acc = fmaf(w.z, hv.z, acc); acc = fmaf(w.w, hv.w, acc);
        }
        O[rr * 24 + c] = acc;
    }
    __syncthreads();
    if (MODE == 0) {
        for (int e = tid; e < 16 * 12; e += 256) {
            int rr = e / 12, pr = e - rr * 12;
            float p0 = O[rr * 24 + 2*pr], p1 = O[rr * 24 + 2*pr + 1];
            float q0, q1; hexq(p0, p1, q0, q1);
            out[(row0 + rr) * 24 + 2*pr]     = q0;
            out[(row0 + rr) * 24 + 2*pr + 1] = q1;
        }
    } else {
        for (int e = tid; e < 16 * 24; e += 256) {
            int rr = e / 24, c = e - rr * 24;
            out[(row0 + rr) * 24 + c] = O[rr * 24 + c] + sym[c];
        }
    }
}

// ---------------------------------------------------------------------------
// K5: Monte-Carlo likelihood. One block per batch element, one thread per MC
// sample. Prior params via wave-uniform global reads (-> s_load); u2^T in LDS
// (stride-1 lane access, conflict-free).
// ---------------------------------------------------------------------------
__global__ __launch_bounds__(256) void k_mc(
    const float* __restrict__ yhat, const float* __restrict__ u2t,
    const float* __restrict__ eb, float* __restrict__ lik)
{
    __shared__ alignas(16) float sU[24 * 256];
    __shared__ float red[256];
    int tid = threadIdx.x;
    int b = blockIdx.x;
    for (int i = tid; i < 1536; i += 256)
        ((float4*)sU)[i] = ((const float4*)u2t)[i];
    __syncthreads();

    float lp = 0.f;
    for (int c = 0; c < 24; ++c) {
        const float* P = eb + c * 58;      // wave-uniform
        float p = yhat[b * 24 + c] + sU[c * 256 + tid];

        float w00 = P[0], w01 = P[1], w02 = P[2];
        float z0 = fmaf(w00, p, P[3]);
        float z1 = fmaf(w01, p, P[4]);
        float z2 = fmaf(w02, p, P[5]);
        float a0 = P[6], a1 = P[7], a2 = P[8];
        float e0 = tanh_fast(z0), e1 = tanh_fast(z1), e2 = tanh_fast(z2);
        float h0 = fmaf(a0, e0, z0), h1 = fmaf(a1, e1, z1), h2 = fmaf(a2, e2, z2);
        float t0 = w00 * fmaf(a0, fmaf(-e0, e0, 1.f), 1.f);
        float t1 = w01 * fmaf(a1, fmaf(-e1, e1, 1.f), 1.f);
        float t2 = w02 * fmaf(a2, fmaf(-e2, e2, 1.f), 1.f);

#define EB_LAYER(O)                                                            \
        {                                                                      \
            float z0n = fmaf(P[O+0], h0, fmaf(P[O+1], h1, fmaf(P[O+2], h2, P[O+9])));  \
            float z1n = fmaf(P[O+3], h0, fmaf(P[O+4], h1, fmaf(P[O+5], h2, P[O+10]))); \
            float z2n = fmaf(P[O+6], h0, fmaf(P[O+7], h1, fmaf(P[O+8], h2, P[O+11]))); \
            float s0 = fmaf(P[O+0], t0, fmaf(P[O+1], t1, P[O+2] * t2));        \
            float s1 = fmaf(P[O+3], t0, fmaf(P[O+4], t1, P[O+5] * t2));        \
            float s2 = fmaf(P[O+6], t0, fmaf(P[O+7], t1, P[O+8] * t2));        \
            float g0 = P[O+12], g1 = P[O+13], g2 = P[O+14];                    \
            float q0 = tanh_fast(z0n), q1 = tanh_fast(z1n), q2 = tanh_fast(z2n); \
            h0 = fmaf(g0, q0, z0n); h1 = fmaf(g1, q1, z1n); h2 = fmaf(g2, q2, z2n); \
            t0 = s0 * fmaf(g0, fmaf(-q0, q0, 1.f), 1.f);                       \
            t1 = s1 * fmaf(g1, fmaf(-q1, q1, 1.f), 1.f);                       \
            t2 = s2 * fmaf(g2, fmaf(-q2, q2, 1.f), 1.f);                       \
        }
        EB_LAYER(9)
        EB_LAYER(24)
        EB_LAYER(39)
#undef EB_LAYER

        float L = fmaf(P[54], h0, fmaf(P[55], h1, fmaf(P[56], h2, P[57])));
        float T = fmaf(P[54], t0, fmaf(P[55], t1, P[56] * t2));
        float Lc = fminf(fmaxf(L, -30.f), 30.f);
        float sg = rcp_fast(1.f + __expf(-Lc));
        float pdf = sg * (1.f - sg) * T;
        lp += __logf(pdf + 1e-9f);
    }

    // deterministic block logsumexp over the 256 MC samples
    red[tid] = lp;
    __syncthreads();
    for (int s = 128; s > 0; s >>= 1) {
        if (tid < s) red[tid] = fmaxf(red[tid], red[tid + s]);
        __syncthreads();
    }
    float mx = red[0];
    __syncthreads();
    red[tid] = __expf(lp - mx);
    __syncthreads();
    for (int s = 128; s > 0; s >>= 1) {
        if (tid < s) red[tid] += red[tid + s];
        __syncthreads();
    }
    if (tid == 0)
        lik[b] = mx + __logf(red[0]) - 7.271269879190247f;  // -log(NMC) + LOG_VOL
}

// ---------------------------------------------------------------------------
extern "C" void kernel_launch(void* const* d_in, const int* in_sizes, int n_in,
                              void* d_out, int out_size, void* d_ws, size_t ws_size,
                              hipStream_t stream)
{
    (void)in_sizes; (void)n_in; (void)out_size; (void)ws_size;
    const float* x      = (const float*)d_in[0];
    const float* y_mean = (const float*)d_in[1];
    const float* u      = (const float*)d_in[2];
    const float* ga_w0  = (const float*)d_in[3];
    const float* ga_b0  = (const float*)d_in[4];
    const float* ga_w1  = (const float*)d_in[5];
    const float* ga_b1  = (const float*)d_in[6];
    const float* ga_w2  = (const float*)d_in[7];
    const float* ga_b2  = (const float*)d_in[8];
    const float* gs_w0  = (const float*)d_in[9];
    const float* gs_b0  = (const float*)d_in[10];
    const float* gs_w1  = (const float*)d_in[11];
    const float* gs_b1  = (const float*)d_in[12];
    const float* gs_w2  = (const float*)d_in[13];
    const float* gs_b2  = (const float*)d_in[14];
    const float* gac_w0 = (const float*)d_in[15];
    const float* gac_w1 = (const float*)d_in[16];
    const float* gac_w2 = (const float*)d_in[17];
    const float* gsc_w0 = (const float*)d_in[18];
    const float* gsc_w1 = (const float*)d_in[19];
    const float* gsc_w2 = (const float*)d_in[20];
    const float* eb_H0  = (const float*)d_in[21];
    const float* eb_H1  = (const float*)d_in[22];
    const float* eb_H2  = (const float*)d_in[23];
    const float* eb_H3  = (const float*)d_in[24];
    const float* eb_H4  = (const float*)d_in[25];
    const float* eb_b0  = (const float*)d_in[26];
    const float* eb_b1  = (const float*)d_in[27];
    const float* eb_b2  = (const float*)d_in[28];
    const float* eb_b3  = (const float*)d_in[29];
    const float* eb_b4  = (const float*)d_in[30];
    const float* eb_a0  = (const float*)d_in[31];
    const float* eb_a1  = (const float*)d_in[32];
    const float* eb_a2  = (const float*)d_in[33];
    const float* eb_a3  = (const float*)d_in[34];

    float* ws    = (float*)d_ws;
    float* y1    = ws + WS_Y1;
    float* yhat  = ws + WS_YHAT;
    float* yhat1 = ws + WS_YHAT1;
    float* ym    = ws + WS_YM;
    float* u2t   = ws + WS_U2T;
    float* eb    = ws + WS_EB;
    float* xhat  = (float*)d_out;
    float* lik   = (float*)d_out + 98304;

    k_prep<<<1, 256, 0, stream>>>(eb_H0, eb_H1, eb_H2, eb_H3, eb_H4,
                                  eb_b0, eb_b1, eb_b2, eb_b3, eb_b4,
                                  eb_a0, eb_a1, eb_a2, eb_a3, u, eb, u2t);
    k_mlp2<<<ROWS2 / 64, 256, 0, stream>>>(x, ga_w0, ga_b0, ga_w1, ga_b1,
                                           ga_w2, ga_b2, y1);
    k_mean<<<1, 256, 0, stream>>>(y1, y_mean, ym);
    k_mlp24<0><<<NB / 16, 256, 0, stream>>>(y1, gac_w0, gac_w1, gac_w2, ym, yhat);
    k_mlp24<1><<<NB / 16, 256, 0, stream>>>(yhat, gsc_w0, gsc_w1, gsc_w2, ym, yhat1);
    k_mlp2<<<ROWS2 / 64, 256, 0, stream>>>(yhat1, gs_w0, gs_b0, gs_w1, gs_b1,
                                           gs_w2, gs_b2, xhat);
    k_mc<<<NB, 256, 0, stream>>>(yhat, u2t, eb, lik);
}

// Round 2
// 129.473 us; speedup vs baseline: 1.9573x; 1.9573x over previous
//
#include <hip/hip_runtime.h>
#include <hip/hip_bf16.h>
#include <math.h>

// Problem dims
constexpr int NB    = 4096;   // batch
constexpr int NBLKc = 12;
constexpr int NDIMc = 24;
constexpr int NMCc  = 256;
constexpr int ROWS2 = NB * NBLKc;     // 49152 rows for the 2->100->100->2 MLPs

// workspace layout (float offsets)
constexpr size_t WS_Y1    = 0;              // NB*24
constexpr size_t WS_YHAT  = 98304;          // NB*24
constexpr size_t WS_YHAT1 = 196608;         // NB*24
constexpr size_t WS_YM    = 294912;         // 24
constexpr size_t WS_U2T   = 294936;         // 24*256 (transposed: [c][m])
constexpr size_t WS_EB    = 301080;         // 24*58 precomputed prior params
constexpr size_t WS_KMM   = 302472;         // 48 ints (kmin[24], kmax[24])
constexpr size_t WS_TBL   = 302520;         // 24*64*256 table of log(pdf+1e-9)
constexpr size_t WS_END   = WS_TBL + 24 * 64 * 256;   // 695736 floats

constexpr float STEP_ODD = 0.8660254037844386f;   // sqrt(3)/2
constexpr float INV_ODD  = 1.1547005383792517f;   // 2/sqrt(3)

__device__ __forceinline__ float lrelu(float x) { return x >= 0.f ? x : 0.01f * x; }

__device__ __forceinline__ float rcp_fast(float x) { return __builtin_amdgcn_rcpf(x); }

// fast tanh via exp, safe for all x (clamped so exp stays finite)
__device__ __forceinline__ float tanh_fast(float x) {
    float xx = fminf(fmaxf(x, -15.f), 15.f);
    float e = __expf(xx + xx);
    return fmaf(-2.f, rcp_fast(e + 1.f), 1.f);
}

// stable softplus (fast-math version for the 100-wide MLPs)
__device__ __forceinline__ float splus(float x) {
    return fmaxf(x, 0.f) + __logf(1.f + __expf(-fabsf(x)));
}
// precise softplus for the (tiny) parameter precompute
__device__ __forceinline__ float splus_precise(float x) {
    return fmaxf(x, 0.f) + log1pf(expf(-fabsf(x)));
}

// exact A2 hex lattice nearest-point quantizer; matches jnp.round (rint = RNE)
__device__ __forceinline__ void hexq(float p0, float p1, float& q0, float& q1) {
    const float S3 = 1.7320508075688772f;
    const float H3 = 0.8660254037844386f;
    float c00 = rintf(p0);
    float c01 = rintf(p1 / S3) * S3;
    float c10 = rintf(p0 - 0.5f) + 0.5f;
    float c11 = rintf((p1 - H3) / S3) * S3 + H3;
    float d0 = (p0 - c00) * (p0 - c00) + (p1 - c01) * (p1 - c01);
    float d1 = (p0 - c10) * (p0 - c10) + (p1 - c11) * (p1 - c11);
    bool take0 = d0 <= d1;
    q0 = take0 ? c00 : c10;
    q1 = take0 ? c01 : c11;
}

// per-channel prior chain: log(pdf + 1e-9) at point p, params P (58 floats)
__device__ __forceinline__ float logpdf_ch(const float* __restrict__ P, float p) {
    float w00 = P[0], w01 = P[1], w02 = P[2];
    float z0 = fmaf(w00, p, P[3]);
    float z1 = fmaf(w01, p, P[4]);
    float z2 = fmaf(w02, p, P[5]);
    float a0 = P[6], a1 = P[7], a2 = P[8];
    float e0 = tanh_fast(z0), e1 = tanh_fast(z1), e2 = tanh_fast(z2);
    float h0 = fmaf(a0, e0, z0), h1 = fmaf(a1, e1, z1), h2 = fmaf(a2, e2, z2);
    float t0 = w00 * fmaf(a0, fmaf(-e0, e0, 1.f), 1.f);
    float t1 = w01 * fmaf(a1, fmaf(-e1, e1, 1.f), 1.f);
    float t2 = w02 * fmaf(a2, fmaf(-e2, e2, 1.f), 1.f);

#define EB_LAYER(O)                                                            \
    {                                                                          \
        float z0n = fmaf(P[O+0], h0, fmaf(P[O+1], h1, fmaf(P[O+2], h2, P[O+9])));  \
        float z1n = fmaf(P[O+3], h0, fmaf(P[O+4], h1, fmaf(P[O+5], h2, P[O+10]))); \
        float z2n = fmaf(P[O+6], h0, fmaf(P[O+7], h1, fmaf(P[O+8], h2, P[O+11]))); \
        float s0 = fmaf(P[O+0], t0, fmaf(P[O+1], t1, P[O+2] * t2));            \
        float s1 = fmaf(P[O+3], t0, fmaf(P[O+4], t1, P[O+5] * t2));            \
        float s2 = fmaf(P[O+6], t0, fmaf(P[O+7], t1, P[O+8] * t2));            \
        float g0 = P[O+12], g1 = P[O+13], g2 = P[O+14];                        \
        float q0 = tanh_fast(z0n), q1 = tanh_fast(z1n), q2 = tanh_fast(z2n);   \
        h0 = fmaf(g0, q0, z0n); h1 = fmaf(g1, q1, z1n); h2 = fmaf(g2, q2, z2n); \
        t0 = s0 * fmaf(g0, fmaf(-q0, q0, 1.f), 1.f);                           \
        t1 = s1 * fmaf(g1, fmaf(-q1, q1, 1.f), 1.f);                           \
        t2 = s2 * fmaf(g2, fmaf(-q2, q2, 1.f), 1.f);                           \
    }
    EB_LAYER(9)
    EB_LAYER(24)
    EB_LAYER(39)
#undef EB_LAYER

    float L = fmaf(P[54], h0, fmaf(P[55], h1, fmaf(P[56], h2, P[57])));
    float T = fmaf(P[54], t0, fmaf(P[55], t1, P[56] * t2));
    float Lc = fminf(fmaxf(L, -30.f), 30.f);
    float sg = rcp_fast(1.f + __expf(-Lc));
    float pdf = sg * (1.f - sg) * T;
    return __logf(pdf + 1e-9f);
}

// ---------------------------------------------------------------------------
// K0: precompute prior params (softplus(H), tanh(a)) and u2^T = (uG - hexq(uG))^T
// layout per channel c (58 floats): w0[3] b0[3] a0[3] | w1[9] b1[3] a1[3] |
//   w2[9] b2[3] a2[3] | w3[9] b3[3] a3[3] | w4[3] b4[1]
// ---------------------------------------------------------------------------
__global__ __launch_bounds__(256) void k_prep(
    const float* __restrict__ H0p, const float* __restrict__ H1p,
    const float* __restrict__ H2p, const float* __restrict__ H3p,
    const float* __restrict__ H4p,
    const float* __restrict__ b0p, const float* __restrict__ b1p,
    const float* __restrict__ b2p, const float* __restrict__ b3p,
    const float* __restrict__ b4p,
    const float* __restrict__ a0p, const float* __restrict__ a1p,
    const float* __restrict__ a2p, const float* __restrict__ a3p,
    const float* __restrict__ u, float* __restrict__ eb, float* __restrict__ u2t)
{
    int tid = threadIdx.x;
    if (tid < 24) {
        int c = tid;
        float* P = eb + c * 58;
        for (int j = 0; j < 3; ++j) P[j]      = splus_precise(H0p[c*3+j]);
        for (int j = 0; j < 3; ++j) P[3+j]    = b0p[c*3+j];
        for (int j = 0; j < 3; ++j) P[6+j]    = tanhf(a0p[c*3+j]);
        for (int j = 0; j < 9; ++j) P[9+j]    = splus_precise(H1p[c*9+j]);
        for (int j = 0; j < 3; ++j) P[18+j]   = b1p[c*3+j];
        for (int j = 0; j < 3; ++j) P[21+j]   = tanhf(a1p[c*3+j]);
        for (int j = 0; j < 9; ++j) P[24+j]   = splus_precise(H2p[c*9+j]);
        for (int j = 0; j < 3; ++j) P[33+j]   = b2p[c*3+j];
        for (int j = 0; j < 3; ++j) P[36+j]   = tanhf(a2p[c*3+j]);
        for (int j = 0; j < 9; ++j) P[39+j]   = splus_precise(H3p[c*9+j]);
        for (int j = 0; j < 3; ++j) P[48+j]   = b3p[c*3+j];
        for (int j = 0; j < 3; ++j) P[51+j]   = tanhf(a3p[c*3+j]);
        for (int j = 0; j < 3; ++j) P[54+j]   = splus_precise(H4p[c*3+j]);
        P[57] = b4p[c];
    }
    int m = tid;
    if (m < 256) {
        for (int j = 0; j < 12; ++j) {
            float a  = u[m*24 + 2*j];
            float bb = u[m*24 + 2*j + 1];
            float p0 = fmaf(0.5f, bb, a);
            float p1 = 0.8660254037844386f * bb;
            float q0, q1; hexq(p0, p1, q0, q1);
            u2t[(2*j)   * 256 + m] = p0 - q0;
            u2t[(2*j+1) * 256 + m] = p1 - q1;
        }
    }
}

// ---------------------------------------------------------------------------
// K1/K4: per-row MLP 2 -> 100 (lrelu) -> 100 (lrelu) -> 2 over 49152 rows.
// ---------------------------------------------------------------------------
__global__ __launch_bounds__(256) void k_mlp2(
    const float* __restrict__ in,
    const float* __restrict__ w0, const float* __restrict__ b0,
    const float* __restrict__ w1, const float* __restrict__ b1,
    const float* __restrict__ w2, const float* __restrict__ b2,
    float* __restrict__ out)
{
    __shared__ alignas(16) float sw1[10000];
    __shared__ alignas(16) float sw0[200];
    __shared__ float sb0[100], sb1[100], sw2[200], sb2[2];
    int tid = threadIdx.x;
    for (int i = tid; i < 10000; i += 256) sw1[i] = w1[i];
    for (int i = tid; i < 200; i += 256) { sw0[i] = w0[i]; sw2[i] = w2[i]; }
    for (int i = tid; i < 100; i += 256) { sb0[i] = b0[i]; sb1[i] = b1[i]; }
    if (tid < 2) sb2[tid] = b2[tid];
    __syncthreads();

    int r = tid >> 2, q = tid & 3;
    int row = blockIdx.x * 64 + r;
    float x0 = in[2*row], x1 = in[2*row + 1];

    float h[100];
#pragma unroll
    for (int j = 0; j < 100; ++j)
        h[j] = lrelu(fmaf(sw0[2*j], x0, fmaf(sw0[2*j+1], x1, sb0[j])));

    float y0 = 0.f, y1 = 0.f;
    int i0 = q * 25;
    for (int i = i0; i < i0 + 25; ++i) {
        const float4* wr = (const float4*)&sw1[i * 100];
        float s = sb1[i];
#pragma unroll
        for (int jj = 0; jj < 25; ++jj) {
            float4 w = wr[jj];
            s = fmaf(w.x, h[4*jj], s);
            s = fmaf(w.y, h[4*jj+1], s);
            s = fmaf(w.z, h[4*jj+2], s);
            s = fmaf(w.w, h[4*jj+3], s);
        }
        float a = lrelu(s);
        y0 = fmaf(sw2[i], a, y0);
        y1 = fmaf(sw2[100 + i], a, y1);
    }
    y0 += __shfl_xor(y0, 1); y0 += __shfl_xor(y0, 2);
    y1 += __shfl_xor(y1, 1); y1 += __shfl_xor(y1, 2);
    if (q == 0) {
        out[2*row]     = y0 + sb2[0];
        out[2*row + 1] = y1 + sb2[1];
    }
}

// ---------------------------------------------------------------------------
// K2: deterministic mean over batch + EMA
// ---------------------------------------------------------------------------
__global__ __launch_bounds__(256) void k_mean(
    const float* __restrict__ y1, const float* __restrict__ y_mean,
    float* __restrict__ ym)
{
    __shared__ float red[96];
    int tid = threadIdx.x;
    float acc[24];
#pragma unroll
    for (int c = 0; c < 24; ++c) acc[c] = 0.f;
    for (int b = tid; b < NB; b += 256) {
        const float4* rp = (const float4*)&y1[b * 24];
#pragma unroll
        for (int k = 0; k < 6; ++k) {
            float4 v = rp[k];
            acc[4*k]   += v.x; acc[4*k+1] += v.y;
            acc[4*k+2] += v.z; acc[4*k+3] += v.w;
        }
    }
#pragma unroll
    for (int c = 0; c < 24; ++c) {
        float v = acc[c];
        for (int off = 1; off < 64; off <<= 1) v += __shfl_xor(v, off);
        if ((tid & 63) == 0) red[(tid >> 6) * 24 + c] = v;
    }
    __syncthreads();
    if (tid < 24) {
        float sv = red[tid] + red[24 + tid] + red[48 + tid] + red[72 + tid];
        ym[tid] = fmaf(0.05f, y_mean[tid], 0.95f * (sv * (1.0f / NB)));
    }
}

// ---------------------------------------------------------------------------
// K3: softplus MLP 24 -> 100 -> 100 -> 24 (no biases), tiled 16 rows/block.
// ---------------------------------------------------------------------------
template <int MODE>
__global__ __launch_bounds__(256) void k_mlp24(
    const float* __restrict__ in,
    const float* __restrict__ w0, const float* __restrict__ w1,
    const float* __restrict__ w2,
    const float* __restrict__ ymg, float* __restrict__ out)
{
    __shared__ alignas(16) float sw0[2400];
    __shared__ alignas(16) float sw1[10000];
    __shared__ alignas(16) float sw2[2400];
    __shared__ alignas(16) float X[16 * 24];
    __shared__ alignas(16) float Ha[16 * 100];
    __shared__ alignas(16) float Hb[16 * 100];
    __shared__ float O[16 * 24];
    __shared__ float sym[24];

    int tid = threadIdx.x;
    int row0 = blockIdx.x * 16;
    for (int i = tid; i < 2400; i += 256) { sw0[i] = w0[i]; sw2[i] = w2[i]; }
    for (int i = tid; i < 10000; i += 256) sw1[i] = w1[i];
    if (tid < 24) sym[tid] = ymg[tid];
    for (int e = tid; e < 16 * 24; e += 256) {
        float v = in[row0 * 24 + e];
        if (MODE == 0) v -= ymg[e % 24];
        X[e] = v;
    }
    __syncthreads();

    int r = tid >> 4, s = tid & 15;
    for (int k = 0; k < 7; ++k) {
        int i = s + 16 * k;
        if (i < 100) {
            const float4* wr = (const float4*)&sw0[i * 24];
            const float4* xr = (const float4*)&X[r * 24];
            float acc = 0.f;
#pragma unroll
            for (int jj = 0; jj < 6; ++jj) {
                float4 w = wr[jj], xv = xr[jj];
                acc = fmaf(w.x, xv.x, acc); acc = fmaf(w.y, xv.y, acc);
                acc = fmaf(w.z, xv.z, acc); acc = fmaf(w.w, xv.w, acc);
            }
            Ha[r * 100 + i] = splus(acc);
        }
    }
    __syncthreads();
    for (int k = 0; k < 7; ++k) {
        int i = s + 16 * k;
        if (i < 100) {
            const float4* wr = (const float4*)&sw1[i * 100];
            const float4* hr = (const float4*)&Ha[r * 100];
            float acc = 0.f;
#pragma unroll
            for (int jj = 0; jj < 25; ++jj) {
                float4 w = wr[jj], hv = hr[jj];
                acc = fmaf(w.x, hv.x, acc); acc = fmaf(w.y, hv.y, acc);
                acc = fmaf(w.z, hv.z, acc); acc = fmaf(w.w, hv.w, acc);
            }
            Hb[r * 100 + i] = splus(acc);
        }
    }
    __syncthreads();
    for (int e = tid; e < 16 * 24; e += 256) {
        int rr = e / 24, c = e - rr * 24;
        const float4* wr = (const float4*)&sw2[c * 100];
        const float4* hr = (const float4*)&Hb[rr * 100];
        float acc = 0.f;
#pragma unroll
        for (int jj = 0; jj < 25; ++jj) {
            float4 w = wr[jj], hv = hr[jj];
            acc = fmaf(w.x, hv.x, acc); acc = fmaf(w.y, hv.y, acc);
            acc = fmaf(w.z, hv.z, acc); acc = fmaf(w.w, hv.w, acc);
        }
        O[rr * 24 + c] = acc;
    }
    __syncthreads();
    if (MODE == 0) {
        for (int e = tid; e < 16 * 12; e += 256) {
            int rr = e / 12, pr = e - rr * 12;
            float p0 = O[rr * 24 + 2*pr], p1 = O[rr * 24 + 2*pr + 1];
            float q0, q1; hexq(p0, p1, q0, q1);
            out[(row0 + rr) * 24 + 2*pr]     = q0;
            out[(row0 + rr) * 24 + 2*pr + 1] = q1;
        }
    } else {
        for (int e = tid; e < 16 * 24; e += 256) {
            int rr = e / 24, c = e - rr * 24;
            out[(row0 + rr) * 24 + c] = O[rr * 24 + c] + sym[c];
        }
    }
}

// ---------------------------------------------------------------------------
// K5a: per-channel lattice-index min/max of yhat (24 blocks, deterministic)
// ---------------------------------------------------------------------------
__global__ __launch_bounds__(256) void k_minmax(
    const float* __restrict__ yhat, int* __restrict__ kmm)
{
    __shared__ int smin[4], smax[4];
    int c = blockIdx.x;
    float inv = (c & 1) ? INV_ODD : 2.0f;
    int tid = threadIdx.x;
    int kmin = 0x7fffffff, kmax = 0x80000000;
    for (int b = tid; b < NB; b += 256) {
        int k = (int)rintf(yhat[b * 24 + c] * inv);
        kmin = min(kmin, k);
        kmax = max(kmax, k);
    }
    for (int off = 1; off < 64; off <<= 1) {
        kmin = min(kmin, __shfl_xor(kmin, off));
        kmax = max(kmax, __shfl_xor(kmax, off));
    }
    if ((tid & 63) == 0) { smin[tid >> 6] = kmin; smax[tid >> 6] = kmax; }
    __syncthreads();
    if (tid == 0) {
        kmm[c]      = min(min(smin[0], smin[1]), min(smin[2], smin[3]));
        kmm[24 + c] = max(max(smax[0], smax[1]), max(smax[2], smax[3]));
    }
}

// ---------------------------------------------------------------------------
// K5b: build T[c][v][m] = logpdf_c((kmin_c+v)*step_c + u2[c,m]); grid 24*64
// ---------------------------------------------------------------------------
__global__ __launch_bounds__(256) void k_table(
    const float* __restrict__ eb, const float* __restrict__ u2t,
    const int* __restrict__ kmm, float* __restrict__ tbl)
{
    int cv = blockIdx.x;
    int c = cv >> 6, v = cv & 63;
    int m = threadIdx.x;
    float step = (c & 1) ? STEP_ODD : 0.5f;
    float val = (float)(kmm[c] + v) * step;
    float p = val + u2t[c * 256 + m];
    tbl[cv * 256 + m] = logpdf_ch(eb + c * 58, p);
}

// ---------------------------------------------------------------------------
// K5c: MC likelihood via table gather. Block = batch element, thread = sample.
// ---------------------------------------------------------------------------
__global__ __launch_bounds__(256) void k_mc_tbl(
    const float* __restrict__ yhat, const float* __restrict__ u2t,
    const float* __restrict__ eb, const int* __restrict__ kmm,
    const float* __restrict__ tbl, float* __restrict__ lik)
{
    __shared__ float red[256];
    int tid = threadIdx.x;
    int b = blockIdx.x;

    float y[24];
    const float4* yr = (const float4*)(yhat + b * 24);
#pragma unroll
    for (int k4 = 0; k4 < 6; ++k4) {
        float4 t = yr[k4];
        y[4*k4] = t.x; y[4*k4+1] = t.y; y[4*k4+2] = t.z; y[4*k4+3] = t.w;
    }

    float lp = 0.f;
    unsigned miss = 0;
#pragma unroll
    for (int c = 0; c < 24; ++c) {
        float inv = (c & 1) ? INV_ODD : 2.0f;
        int k = (int)rintf(y[c] * inv);
        int idx = k - kmm[c];
        if (idx >= 0 && idx < 64)
            lp += tbl[(c * 64 + idx) * 256 + tid];
        else
            miss |= (1u << c);
    }
    // rare wave-uniform fallback: channel range exceeded 64 lattice slots
    while (miss) {
        int c = __ffs(miss) - 1;
        miss &= miss - 1;
        lp += logpdf_ch(eb + c * 58, y[c] + u2t[c * 256 + tid]);
    }

    // deterministic block logsumexp over the 256 MC samples
    red[tid] = lp;
    __syncthreads();
    for (int s = 128; s > 0; s >>= 1) {
        if (tid < s) red[tid] = fmaxf(red[tid], red[tid + s]);
        __syncthreads();
    }
    float mx = red[0];
    __syncthreads();
    red[tid] = __expf(lp - mx);
    __syncthreads();
    for (int s = 128; s > 0; s >>= 1) {
        if (tid < s) red[tid] += red[tid + s];
        __syncthreads();
    }
    if (tid == 0)
        lik[b] = mx + __logf(red[0]) - 7.271269879190247f;  // -log(NMC) + LOG_VOL
}

// ---------------------------------------------------------------------------
// K5 (fallback when ws too small): original direct MC kernel
// ---------------------------------------------------------------------------
__global__ __launch_bounds__(256) void k_mc_direct(
    const float* __restrict__ yhat, const float* __restrict__ u2t,
    const float* __restrict__ eb, float* __restrict__ lik)
{
    __shared__ alignas(16) float sU[24 * 256];
    __shared__ float red[256];
    int tid = threadIdx.x;
    int b = blockIdx.x;
    for (int i = tid; i < 1536; i += 256)
        ((float4*)sU)[i] = ((const float4*)u2t)[i];
    __syncthreads();

    float lp = 0.f;
    for (int c = 0; c < 24; ++c) {
        float p = yhat[b * 24 + c] + sU[c * 256 + tid];
        lp += logpdf_ch(eb + c * 58, p);
    }

    red[tid] = lp;
    __syncthreads();
    for (int s = 128; s > 0; s >>= 1) {
        if (tid < s) red[tid] = fmaxf(red[tid], red[tid + s]);
        __syncthreads();
    }
    float mx = red[0];
    __syncthreads();
    red[tid] = __expf(lp - mx);
    __syncthreads();
    for (int s = 128; s > 0; s >>= 1) {
        if (tid < s) red[tid] += red[tid + s];
        __syncthreads();
    }
    if (tid == 0)
        lik[b] = mx + __logf(red[0]) - 7.271269879190247f;
}

// ---------------------------------------------------------------------------
extern "C" void kernel_launch(void* const* d_in, const int* in_sizes, int n_in,
                              void* d_out, int out_size, void* d_ws, size_t ws_size,
                              hipStream_t stream)
{
    (void)in_sizes; (void)n_in; (void)out_size;
    const float* x      = (const float*)d_in[0];
    const float* y_mean = (const float*)d_in[1];
    const float* u      = (const float*)d_in[2];
    const float* ga_w0  = (const float*)d_in[3];
    const float* ga_b0  = (const float*)d_in[4];
    const float* ga_w1  = (const float*)d_in[5];
    const float* ga_b1  = (const float*)d_in[6];
    const float* ga_w2  = (const float*)d_in[7];
    const float* ga_b2  = (const float*)d_in[8];
    const float* gs_w0  = (const float*)d_in[9];
    const float* gs_b0  = (const float*)d_in[10];
    const float* gs_w1  = (const float*)d_in[11];
    const float* gs_b1  = (const float*)d_in[12];
    const float* gs_w2  = (const float*)d_in[13];
    const float* gs_b2  = (const float*)d_in[14];
    const float* gac_w0 = (const float*)d_in[15];
    const float* gac_w1 = (const float*)d_in[16];
    const float* gac_w2 = (const float*)d_in[17];
    const float* gsc_w0 = (const float*)d_in[18];
    const float* gsc_w1 = (const float*)d_in[19];
    const float* gsc_w2 = (const float*)d_in[20];
    const float* eb_H0  = (const float*)d_in[21];
    const float* eb_H1  = (const float*)d_in[22];
    const float* eb_H2  = (const float*)d_in[23];
    const float* eb_H3  = (const float*)d_in[24];
    const float* eb_H4  = (const float*)d_in[25];
    const float* eb_b0  = (const float*)d_in[26];
    const float* eb_b1  = (const float*)d_in[27];
    const float* eb_b2  = (const float*)d_in[28];
    const float* eb_b3  = (const float*)d_in[29];
    const float* eb_b4  = (const float*)d_in[30];
    const float* eb_a0  = (const float*)d_in[31];
    const float* eb_a1  = (const float*)d_in[32];
    const float* eb_a2  = (const float*)d_in[33];
    const float* eb_a3  = (const float*)d_in[34];

    float* ws    = (float*)d_ws;
    float* y1    = ws + WS_Y1;
    float* yhat  = ws + WS_YHAT;
    float* yhat1 = ws + WS_YHAT1;
    float* ym    = ws + WS_YM;
    float* u2t   = ws + WS_U2T;
    float* eb    = ws + WS_EB;
    int*   kmm   = (int*)(ws + WS_KMM);
    float* tbl   = ws + WS_TBL;
    float* xhat  = (float*)d_out;
    float* lik   = (float*)d_out + 98304;

    bool use_tbl = ws_size >= WS_END * sizeof(float);

    k_prep<<<1, 256, 0, stream>>>(eb_H0, eb_H1, eb_H2, eb_H3, eb_H4,
                                  eb_b0, eb_b1, eb_b2, eb_b3, eb_b4,
                                  eb_a0, eb_a1, eb_a2, eb_a3, u, eb, u2t);
    k_mlp2<<<ROWS2 / 64, 256, 0, stream>>>(x, ga_w0, ga_b0, ga_w1, ga_b1,
                                           ga_w2, ga_b2, y1);
    k_mean<<<1, 256, 0, stream>>>(y1, y_mean, ym);
    k_mlp24<0><<<NB / 16, 256, 0, stream>>>(y1, gac_w0, gac_w1, gac_w2, ym, yhat);
    if (use_tbl) {
        k_minmax<<<24, 256, 0, stream>>>(yhat, kmm);
        k_table<<<24 * 64, 256, 0, stream>>>(eb, u2t, kmm, tbl);
    }
    k_mlp24<1><<<NB / 16, 256, 0, stream>>>(yhat, gsc_w0, gsc_w1, gsc_w2, ym, yhat1);
    k_mlp2<<<ROWS2 / 64, 256, 0, stream>>>(yhat1, gs_w0, gs_b0, gs_w1, gs_b1,
                                           gs_w2, gs_b2, xhat);
    if (use_tbl)
        k_mc_tbl<<<NB, 256, 0, stream>>>(yhat, u2t, eb, kmm, tbl, lik);
    else
        k_mc_direct<<<NB, 256, 0, stream>>>(yhat, u2t, eb, lik);
}